// Round 1
// baseline (1538.967 us; speedup 1.0000x reference)
//
#include <hip/hip_runtime.h>
#include <hip/hip_bf16.h>
#include <math.h>

#define BATCH   16
#define SEQL    512
#define NVARS   32
#define PATCHL  16
#define LTOK    32            // SEQL/PATCHL
#define DMODEL  128
#define NLAYER  2
#define DIN     256           // d_inner
#define DSTATE  16
#define DTRANK  8
#define DCONV   4
#define PRED    96
#define TOK     1024          // NVARS*LTOK tokens per batch item
#define NTOK    (BATCH*TOK)   // 16384
#define EPSF    1e-5f

// ---------------------------------------------------------------------------
// K1: per-(b,c) instance norm over time + patch embedding
// ---------------------------------------------------------------------------
__global__ __launch_bounds__(256) void k_instnorm_patch(
    const float* __restrict__ x_enc, const float* __restrict__ patch_w,
    float* __restrict__ x, float* __restrict__ means, float* __restrict__ stdev)
{
    int bc = blockIdx.x;          // b*32 + c
    int b = bc >> 5, c = bc & 31;
    __shared__ float xe[SEQL];
    __shared__ float pw[DMODEL * PATCHL];
    __shared__ float red[8];
    int tid = threadIdx.x;

    float v0 = x_enc[((size_t)b * SEQL + tid) * NVARS + c];
    float v1 = x_enc[((size_t)b * SEQL + tid + 256) * NVARS + c];
    for (int i = tid; i < DMODEL * PATCHL; i += 256) pw[i] = patch_w[i];

    float s = v0 + v1;
    for (int o = 1; o < 64; o <<= 1) s += __shfl_xor(s, o, 64);
    if ((tid & 63) == 0) red[tid >> 6] = s;
    __syncthreads();
    float mean = (red[0] + red[1] + red[2] + red[3]) * (1.f / 512.f);

    float d0 = v0 - mean, d1 = v1 - mean;
    float q = d0 * d0 + d1 * d1;
    for (int o = 1; o < 64; o <<= 1) q += __shfl_xor(q, o, 64);
    if ((tid & 63) == 0) red[4 + (tid >> 6)] = q;
    __syncthreads();
    float var = (red[4] + red[5] + red[6] + red[7]) * (1.f / 512.f);
    float sd = sqrtf(var + EPSF);
    float rsd = 1.f / sd;
    if (tid == 0) { means[bc] = mean; stdev[bc] = sd; }

    xe[tid] = d0 * rsd;
    xe[tid + 256] = d1 * rsd;
    __syncthreads();

    // enc[b, c*32+l, dm] = sum_p xe[l*16+p] * pw[dm*16+p]
    size_t base = ((size_t)b * TOK + (size_t)c * LTOK) * DMODEL;
    for (int o = tid; o < LTOK * DMODEL; o += 256) {
        int l = o >> 7, dm = o & 127;
        float acc = 0.f;
        #pragma unroll
        for (int p = 0; p < PATCHL; p++) acc += xe[l * PATCHL + p] * pw[dm * PATCHL + p];
        x[base + o] = acc;
    }
}

// ---------------------------------------------------------------------------
// K2: RMSNorm over last dim (128). One wave per token.
// ---------------------------------------------------------------------------
__global__ __launch_bounds__(256) void k_rmsnorm(
    const float* __restrict__ in, const float* __restrict__ w,
    float* __restrict__ out)
{
    int wave = threadIdx.x >> 6, lane = threadIdx.x & 63;
    int tok = blockIdx.x * 4 + wave;
    const float* r = in + (size_t)tok * DMODEL;
    float a = r[lane], bv = r[lane + 64];
    float q = a * a + bv * bv;
    for (int o = 1; o < 64; o <<= 1) q += __shfl_xor(q, o, 64);
    float rms = rsqrtf(q * (1.f / DMODEL) + EPSF);
    float* o_ = out + (size_t)tok * DMODEL;
    o_[lane]      = a  * rms * w[lane];
    o_[lane + 64] = bv * rms * w[lane + 64];
}

// ---------------------------------------------------------------------------
// K3: generic f32 GEMM  C[M,N] (+)= A[M,K] @ W[N,K]^T   (row-major all)
// 64x64 tile, BK=16, 256 threads, 4x4 micro-tile.
// ---------------------------------------------------------------------------
template <bool ADD>
__global__ __launch_bounds__(256) void gemm_nt(
    const float* __restrict__ A, const float* __restrict__ W,
    float* __restrict__ C, int M, int N, int K)
{
    const int BM = 64, BN = 64, BK = 16;
    __shared__ float As[BK][BM + 1];
    __shared__ float Ws[BK][BN + 1];
    int bm = blockIdx.y * BM, bn = blockIdx.x * BN;
    int tid = threadIdx.x;
    int tx = tid & 15, ty = tid >> 4;
    float acc[4][4] = {};

    for (int k0 = 0; k0 < K; k0 += BK) {
        for (int i = tid; i < BM * BK; i += 256) {
            int m = i / BK, k = i % BK;
            float v = 0.f;
            if (bm + m < M) v = A[(size_t)(bm + m) * K + k0 + k];
            As[k][m] = v;
        }
        for (int i = tid; i < BN * BK; i += 256) {
            int n = i / BK, k = i % BK;
            float v = 0.f;
            if (bn + n < N) v = W[(size_t)(bn + n) * K + k0 + k];
            Ws[k][n] = v;
        }
        __syncthreads();
        #pragma unroll
        for (int k = 0; k < BK; k++) {
            float a[4], w[4];
            #pragma unroll
            for (int i = 0; i < 4; i++) a[i] = As[k][ty * 4 + i];
            #pragma unroll
            for (int j = 0; j < 4; j++) w[j] = Ws[k][tx * 4 + j];
            #pragma unroll
            for (int i = 0; i < 4; i++)
                #pragma unroll
                for (int j = 0; j < 4; j++) acc[i][j] += a[i] * w[j];
        }
        __syncthreads();
    }
    for (int i = 0; i < 4; i++) {
        int m = bm + ty * 4 + i;
        if (m >= M) continue;
        for (int j = 0; j < 4; j++) {
            int n = bn + tx * 4 + j;
            if (n >= N) continue;
            size_t idx = (size_t)m * N + n;
            if (ADD) C[idx] += acc[i][j]; else C[idx] = acc[i][j];
        }
    }
}

// ---------------------------------------------------------------------------
// K4: causal depthwise conv (k=4) + bias + SiLU.  xs_ = xz[..., 0:256]
// ---------------------------------------------------------------------------
__global__ __launch_bounds__(256) void k_conv(
    const float* __restrict__ xz, const float* __restrict__ cw,
    const float* __restrict__ cb, float* __restrict__ u)
{
    int idx = blockIdx.x * 256 + threadIdx.x;   // b*1024*256 total
    int d = idx & 255;
    int t = (idx >> 8) & 1023;
    int b = idx >> 18;
    const float* col = xz + ((size_t)b * TOK) * 512 + d;
    float acc = cb[d];
    #pragma unroll
    for (int j = 0; j < DCONV; j++) {
        int tt = t - (DCONV - 1) + j;
        if (tt >= 0) acc += col[(size_t)tt * 512] * cw[d * DCONV + j];
    }
    u[idx] = acc / (1.f + __expf(-acc));   // silu
}

// ---------------------------------------------------------------------------
// K5: dt = softplus(dt_raw @ dt_w^T + dt_b)
// ---------------------------------------------------------------------------
__global__ __launch_bounds__(256) void k_dt(
    const float* __restrict__ xdbl, const float* __restrict__ dtw,
    const float* __restrict__ dtb_, float* __restrict__ dt)
{
    int idx = blockIdx.x * 256 + threadIdx.x;   // 16384*256
    int d = idx & 255;
    int tok = idx >> 8;
    const float* r = xdbl + (size_t)tok * 40;
    float acc = dtb_[d];
    #pragma unroll
    for (int j = 0; j < DTRANK; j++) acc += r[j] * dtw[d * DTRANK + j];
    dt[idx] = (acc > 20.f) ? acc : log1pf(__expf(acc));
}

// ---------------------------------------------------------------------------
// K6: selective scan. Block = (b, dgroup of 16 d). 256 thr = 16 d x 16 n.
// Writes y = (sum_n h*C + u*D) * silu(z).  y may alias dt (chunk-safe).
// ---------------------------------------------------------------------------
#define TCH 128
__global__ __launch_bounds__(256) void k_scan(
    const float* __restrict__ u, const float* __restrict__ dt,
    const float* __restrict__ xdbl, const float* __restrict__ xz,
    const float* __restrict__ A_log, const float* __restrict__ Dp,
    float* __restrict__ y)
{
    int blk = blockIdx.x;            // b*16 + dg
    int b = blk >> 4, dg = blk & 15;
    int tid = threadIdx.x;
    int n = tid & 15, di = tid >> 4;
    int d = dg * 16 + di;
    float Av = -__expf(A_log[d * DSTATE + n]);
    float Dv = Dp[d];

    __shared__ float s_dt[TCH][16];
    __shared__ float s_u [TCH][16];
    __shared__ float s_B [TCH][17];
    __shared__ float s_C [TCH][17];
    __shared__ float s_z [TCH][16];

    float h = 0.f;
    for (int t0 = 0; t0 < TOK; t0 += TCH) {
        __syncthreads();
        for (int i = tid; i < TCH * 16; i += 256) {
            int tl = i >> 4, dd = i & 15;
            size_t tok = (size_t)b * TOK + t0 + tl;
            s_dt[tl][dd] = dt[tok * 256 + dg * 16 + dd];
            s_u [tl][dd] = u [tok * 256 + dg * 16 + dd];
            s_B [tl][dd] = xdbl[tok * 40 + DTRANK + dd];
            s_C [tl][dd] = xdbl[tok * 40 + DTRANK + DSTATE + dd];
            s_z [tl][dd] = xz[tok * 512 + 256 + dg * 16 + dd];
        }
        __syncthreads();
        for (int t = 0; t < TCH; t++) {
            float dtv = s_dt[t][di];
            float uu  = s_u [t][di];
            float Bv  = s_B [t][n];
            float Cv  = s_C [t][n];
            float dA  = __expf(dtv * Av);
            h = dA * h + dtv * Bv * uu;
            float p = h * Cv;
            p += __shfl_xor(p, 1, 64);
            p += __shfl_xor(p, 2, 64);
            p += __shfl_xor(p, 4, 64);
            p += __shfl_xor(p, 8, 64);
            if (n == 0) {
                float zv = s_z[t][di];
                float sz = zv / (1.f + __expf(-zv));
                y[((size_t)b * TOK + t0 + t) * 256 + d] = (p + uu * Dv) * sz;
            }
        }
    }
}

// ---------------------------------------------------------------------------
// K7: head epilogue: out[b,p,c] = (hg[(b*32+c)*96+p] + hb[p]) * stdev + mean
// ---------------------------------------------------------------------------
__global__ __launch_bounds__(256) void k_head_ep(
    const float* __restrict__ hg, const float* __restrict__ hb,
    const float* __restrict__ means, const float* __restrict__ stdev,
    float* __restrict__ out)
{
    int i = blockIdx.x * 256 + threadIdx.x;
    if (i >= BATCH * PRED * NVARS) return;
    int c = i & 31;
    int p = (i >> 5) % PRED;
    int b = i / (PRED * NVARS);
    float v = hg[((size_t)b * NVARS + c) * PRED + p] + hb[p];
    out[i] = v * stdev[b * NVARS + c] + means[b * NVARS + c];
}

// ---------------------------------------------------------------------------
extern "C" void kernel_launch(void* const* d_in, const int* in_sizes, int n_in,
                              void* d_out, int out_size, void* d_ws, size_t ws_size,
                              hipStream_t stream)
{
    const float* x_enc   = (const float*)d_in[0];
    const float* patch_w = (const float*)d_in[4];
    const float* norm_w  = (const float*)d_in[5];
    const float* in_w    = (const float*)d_in[6];
    const float* conv_w  = (const float*)d_in[7];
    const float* conv_b  = (const float*)d_in[8];
    const float* xp_w    = (const float*)d_in[9];
    const float* dt_w    = (const float*)d_in[10];
    const float* dt_b    = (const float*)d_in[11];
    const float* A_log   = (const float*)d_in[12];
    const float* D_skip  = (const float*)d_in[13];
    const float* out_w   = (const float*)d_in[14];
    const float* fnorm_w = (const float*)d_in[15];
    const float* head_w  = (const float*)d_in[16];
    const float* head_b  = (const float*)d_in[17];
    float* out = (float*)d_out;

    float* ws    = (float*)d_ws;
    float* means = ws;                    // 512
    float* stdv  = ws + 512;              // 512
    float* x     = ws + 1024;             // 16384*128
    float* h     = x  + (size_t)NTOK * DMODEL;
    float* xz    = h  + (size_t)NTOK * DMODEL;
    float* u     = xz + (size_t)NTOK * 2 * DIN;
    float* dtb   = u  + (size_t)NTOK * DIN;
    float* xdbl  = dtb + (size_t)NTOK * DIN;
    float* hg    = xdbl + (size_t)NTOK * (DTRANK + 2 * DSTATE);
    float* ybuf  = dtb;                   // alias: safe (chunk read-then-write)

    // 1. instance norm + patch embed -> x
    k_instnorm_patch<<<BATCH * NVARS, 256, 0, stream>>>(x_enc, patch_w, x, means, stdv);

    for (int layer = 0; layer < NLAYER; layer++) {
        const float* nw  = norm_w + layer * DMODEL;
        const float* iw  = in_w   + (size_t)layer * 2 * DIN * DMODEL;
        const float* cw  = conv_w + layer * DIN * DCONV;
        const float* cb  = conv_b + layer * DIN;
        const float* xw  = xp_w   + (size_t)layer * (DTRANK + 2 * DSTATE) * DIN;
        const float* dw  = dt_w   + layer * DIN * DTRANK;
        const float* db  = dt_b   + layer * DIN;
        const float* al  = A_log  + layer * DIN * DSTATE;
        const float* dp  = D_skip + layer * DIN;
        const float* ow  = out_w  + (size_t)layer * DMODEL * DIN;

        // h = rmsnorm(x)
        k_rmsnorm<<<NTOK / 4, 256, 0, stream>>>(x, nw, h);
        // xz = h @ in_w^T   (16384 x 512)
        gemm_nt<false><<<dim3((2 * DIN) / 64, NTOK / 64), 256, 0, stream>>>(
            h, iw, xz, NTOK, 2 * DIN, DMODEL);
        // u = silu(conv(xs_) + b)
        k_conv<<<(NTOK * DIN) / 256, 256, 0, stream>>>(xz, cw, cb, u);
        // xdbl = u @ xp_w^T  (16384 x 40)
        gemm_nt<false><<<dim3(1, NTOK / 64), 256, 0, stream>>>(
            u, xw, xdbl, NTOK, DTRANK + 2 * DSTATE, DIN);
        // dt = softplus(...)
        k_dt<<<(NTOK * DIN) / 256, 256, 0, stream>>>(xdbl, dw, db, dtb);
        // selective scan -> ybuf (fused * silu(z))
        k_scan<<<BATCH * (DIN / 16), 256, 0, stream>>>(u, dtb, xdbl, xz, al, dp, ybuf);
        // x += ybuf @ out_w^T
        gemm_nt<true><<<dim3(DMODEL / 64, NTOK / 64), 256, 0, stream>>>(
            ybuf, ow, x, NTOK, DMODEL, DIN);
    }

    // final norm -> h
    k_rmsnorm<<<NTOK / 4, 256, 0, stream>>>(x, fnorm_w, h);
    // head gemm: (512 x 4096) @ (96 x 4096)^T -> hg (512 x 96)
    gemm_nt<false><<<dim3(2, (BATCH * NVARS) / 64), 256, 0, stream>>>(
        h, head_w, hg, BATCH * NVARS, PRED, LTOK * DMODEL);
    // epilogue: de-norm + transpose
    k_head_ep<<<(BATCH * PRED * NVARS + 255) / 256, 256, 0, stream>>>(
        hg, head_b, means, stdv, out);
}

// Round 2
// 911.900 us; speedup vs baseline: 1.6876x; 1.6876x over previous
//
#include <hip/hip_runtime.h>
#include <hip/hip_bf16.h>
#include <math.h>

#define BATCH   16
#define SEQL    512
#define NVARS   32
#define PATCHL  16
#define LTOK    32            // SEQL/PATCHL
#define DMODEL  128
#define NLAYER  2
#define DIN     256           // d_inner
#define DSTATE  16
#define DTRANK  8
#define DCONV   4
#define PRED    96
#define TOK     1024          // NVARS*LTOK tokens per batch item
#define NTOK    (BATCH*TOK)   // 16384
#define EPSF    1e-5f

// ---------------------------------------------------------------------------
// K1: per-(b,c) instance norm over time + patch embedding
// ---------------------------------------------------------------------------
__global__ __launch_bounds__(256) void k_instnorm_patch(
    const float* __restrict__ x_enc, const float* __restrict__ patch_w,
    float* __restrict__ x, float* __restrict__ means, float* __restrict__ stdev)
{
    int bc = blockIdx.x;          // b*32 + c
    int b = bc >> 5, c = bc & 31;
    __shared__ float xe[SEQL];
    __shared__ float pw[DMODEL * PATCHL];
    __shared__ float red[8];
    int tid = threadIdx.x;

    float v0 = x_enc[((size_t)b * SEQL + tid) * NVARS + c];
    float v1 = x_enc[((size_t)b * SEQL + tid + 256) * NVARS + c];
    for (int i = tid; i < DMODEL * PATCHL; i += 256) pw[i] = patch_w[i];

    float s = v0 + v1;
    for (int o = 1; o < 64; o <<= 1) s += __shfl_xor(s, o, 64);
    if ((tid & 63) == 0) red[tid >> 6] = s;
    __syncthreads();
    float mean = (red[0] + red[1] + red[2] + red[3]) * (1.f / 512.f);

    float d0 = v0 - mean, d1 = v1 - mean;
    float q = d0 * d0 + d1 * d1;
    for (int o = 1; o < 64; o <<= 1) q += __shfl_xor(q, o, 64);
    if ((tid & 63) == 0) red[4 + (tid >> 6)] = q;
    __syncthreads();
    float var = (red[4] + red[5] + red[6] + red[7]) * (1.f / 512.f);
    float sd = sqrtf(var + EPSF);
    float rsd = 1.f / sd;
    if (tid == 0) { means[bc] = mean; stdev[bc] = sd; }

    xe[tid] = d0 * rsd;
    xe[tid + 256] = d1 * rsd;
    __syncthreads();

    size_t base = ((size_t)b * TOK + (size_t)c * LTOK) * DMODEL;
    for (int o = tid; o < LTOK * DMODEL; o += 256) {
        int l = o >> 7, dm = o & 127;
        float acc = 0.f;
        #pragma unroll
        for (int p = 0; p < PATCHL; p++) acc += xe[l * PATCHL + p] * pw[dm * PATCHL + p];
        x[base + o] = acc;
    }
}

// ---------------------------------------------------------------------------
// K2: RMSNorm over last dim (128). One wave per token.
// ---------------------------------------------------------------------------
__global__ __launch_bounds__(256) void k_rmsnorm(
    const float* __restrict__ in, const float* __restrict__ w,
    float* __restrict__ out)
{
    int wave = threadIdx.x >> 6, lane = threadIdx.x & 63;
    int tok = blockIdx.x * 4 + wave;
    const float* r = in + (size_t)tok * DMODEL;
    float a = r[lane], bv = r[lane + 64];
    float q = a * a + bv * bv;
    for (int o = 1; o < 64; o <<= 1) q += __shfl_xor(q, o, 64);
    float rms = rsqrtf(q * (1.f / DMODEL) + EPSF);
    float* o_ = out + (size_t)tok * DMODEL;
    o_[lane]      = a  * rms * w[lane];
    o_[lane + 64] = bv * rms * w[lane + 64];
}

// ---------------------------------------------------------------------------
// K3: generic f32 GEMM  C[M,N] (+)= A[M,K] @ W[N,K]^T   (row-major all)
// 64x64 tile, BK=16, 256 threads, 4x4 micro-tile. +4 pad -> aligned b128.
// ---------------------------------------------------------------------------
template <bool ADD>
__global__ __launch_bounds__(256) void gemm_nt(
    const float* __restrict__ A, const float* __restrict__ W,
    float* __restrict__ C, int M, int N, int K)
{
    const int BM = 64, BN = 64, BK = 16;
    __shared__ float As[BK][BM + 4];
    __shared__ float Ws[BK][BN + 4];
    int bm = blockIdx.y * BM, bn = blockIdx.x * BN;
    int tid = threadIdx.x;
    int tx = tid & 15, ty = tid >> 4;
    float acc[4][4] = {};

    for (int k0 = 0; k0 < K; k0 += BK) {
        for (int i = tid; i < BM * BK; i += 256) {
            int m = i / BK, k = i % BK;
            float v = 0.f;
            if (bm + m < M) v = A[(size_t)(bm + m) * K + k0 + k];
            As[k][m] = v;
        }
        for (int i = tid; i < BN * BK; i += 256) {
            int n = i / BK, k = i % BK;
            float v = 0.f;
            if (bn + n < N) v = W[(size_t)(bn + n) * K + k0 + k];
            Ws[k][n] = v;
        }
        __syncthreads();
        #pragma unroll
        for (int k = 0; k < BK; k++) {
            float a[4], w[4];
            #pragma unroll
            for (int i = 0; i < 4; i++) a[i] = As[k][ty * 4 + i];
            #pragma unroll
            for (int j = 0; j < 4; j++) w[j] = Ws[k][tx * 4 + j];
            #pragma unroll
            for (int i = 0; i < 4; i++)
                #pragma unroll
                for (int j = 0; j < 4; j++) acc[i][j] += a[i] * w[j];
        }
        __syncthreads();
    }
    for (int i = 0; i < 4; i++) {
        int m = bm + ty * 4 + i;
        if (m >= M) continue;
        for (int j = 0; j < 4; j++) {
            int n = bn + tx * 4 + j;
            if (n >= N) continue;
            size_t idx = (size_t)m * N + n;
            if (ADD) C[idx] += acc[i][j]; else C[idx] = acc[i][j];
        }
    }
}

// ---------------------------------------------------------------------------
// K4: causal depthwise conv (k=4) + bias + SiLU.  xs_ = xz[..., 0:256]
// ---------------------------------------------------------------------------
__global__ __launch_bounds__(256) void k_conv(
    const float* __restrict__ xz, const float* __restrict__ cw,
    const float* __restrict__ cb, float* __restrict__ u)
{
    int idx = blockIdx.x * 256 + threadIdx.x;
    int d = idx & 255;
    int t = (idx >> 8) & 1023;
    int b = idx >> 18;
    const float* col = xz + ((size_t)b * TOK) * 512 + d;
    float acc = cb[d];
    #pragma unroll
    for (int j = 0; j < DCONV; j++) {
        int tt = t - (DCONV - 1) + j;
        if (tt >= 0) acc += col[(size_t)tt * 512] * cw[d * DCONV + j];
    }
    u[idx] = acc / (1.f + __expf(-acc));   // silu
}

// ---------------------------------------------------------------------------
// K5: dt = softplus(dt_raw @ dt_w^T + dt_b)
// ---------------------------------------------------------------------------
__global__ __launch_bounds__(256) void k_dt(
    const float* __restrict__ xdbl, const float* __restrict__ dtw,
    const float* __restrict__ dtb_, float* __restrict__ dt)
{
    int idx = blockIdx.x * 256 + threadIdx.x;
    int d = idx & 255;
    int tok = idx >> 8;
    const float* r = xdbl + (size_t)tok * 40;
    float acc = dtb_[d];
    #pragma unroll
    for (int j = 0; j < DTRANK; j++) acc += r[j] * dtw[d * DTRANK + j];
    dt[idx] = (acc > 20.f) ? acc : log1pf(__expf(acc));
}

// ---------------------------------------------------------------------------
// K6: selective scan. Block = (b, dgroup of 16 d). 256 thr = 16 d x 16 n.
// ---------------------------------------------------------------------------
#define TCH 128
__global__ __launch_bounds__(256) void k_scan(
    const float* __restrict__ u, const float* __restrict__ dt,
    const float* __restrict__ xdbl, const float* __restrict__ xz,
    const float* __restrict__ A_log, const float* __restrict__ Dp,
    float* __restrict__ y)
{
    int blk = blockIdx.x;            // b*16 + dg
    int b = blk >> 4, dg = blk & 15;
    int tid = threadIdx.x;
    int n = tid & 15, di = tid >> 4;
    int d = dg * 16 + di;
    float Av = -__expf(A_log[d * DSTATE + n]);
    float Dv = Dp[d];

    __shared__ float s_dt[TCH][16];
    __shared__ float s_u [TCH][16];
    __shared__ float s_B [TCH][17];
    __shared__ float s_C [TCH][17];
    __shared__ float s_z [TCH][16];

    float h = 0.f;
    for (int t0 = 0; t0 < TOK; t0 += TCH) {
        __syncthreads();
        for (int i = tid; i < TCH * 16; i += 256) {
            int tl = i >> 4, dd = i & 15;
            size_t tok = (size_t)b * TOK + t0 + tl;
            s_dt[tl][dd] = dt[tok * 256 + dg * 16 + dd];
            s_u [tl][dd] = u [tok * 256 + dg * 16 + dd];
            s_B [tl][dd] = xdbl[tok * 40 + DTRANK + dd];
            s_C [tl][dd] = xdbl[tok * 40 + DTRANK + DSTATE + dd];
            s_z [tl][dd] = xz[tok * 512 + 256 + dg * 16 + dd];
        }
        __syncthreads();
        for (int t = 0; t < TCH; t++) {
            float dtv = s_dt[t][di];
            float uu  = s_u [t][di];
            float Bv  = s_B [t][n];
            float Cv  = s_C [t][n];
            float dA  = __expf(dtv * Av);
            h = dA * h + dtv * Bv * uu;
            float p = h * Cv;
            p += __shfl_xor(p, 1, 64);
            p += __shfl_xor(p, 2, 64);
            p += __shfl_xor(p, 4, 64);
            p += __shfl_xor(p, 8, 64);
            if (n == 0) {
                float zv = s_z[t][di];
                float sz = zv / (1.f + __expf(-zv));
                y[((size_t)b * TOK + t0 + t) * 256 + d] = (p + uu * Dv) * sz;
            }
        }
    }
}

// ---------------------------------------------------------------------------
// K7: fused head: for 2 rows, compute 96 dots (K=4096) + bias + denorm,
// write transposed. 256 blocks x 512 threads; h rows staged in LDS.
// out[b,p,c] = (dot(h[r], head_w[p]) + hb[p]) * stdev[r] + means[r], r=b*32+c
// ---------------------------------------------------------------------------
__global__ __launch_bounds__(512) void k_head(
    const float* __restrict__ hin,    // (512, 4096)
    const float* __restrict__ head_w, // (96, 4096)
    const float* __restrict__ head_b,
    const float* __restrict__ means, const float* __restrict__ stdev,
    float* __restrict__ out)          // (16, 96, 32)
{
    __shared__ float4 hrow[2 * 1024];   // 2 rows x 4096 f32
    int r0 = blockIdx.x * 2;
    int tid = threadIdx.x;
    const float4* src = (const float4*)(hin + (size_t)r0 * 4096);
    for (int i = tid; i < 2048; i += 512) hrow[i] = src[i];
    __syncthreads();

    int w = tid >> 6, l = tid & 63;     // 8 waves x 12 outputs = 96
    float acc0[12], acc1[12];
    #pragma unroll
    for (int j = 0; j < 12; j++) { acc0[j] = 0.f; acc1[j] = 0.f; }

    const float4* hw4 = (const float4*)head_w;
    #pragma unroll 2
    for (int i = 0; i < 16; i++) {
        int k4 = l + 64 * i;            // float4 index within row
        float4 h0 = hrow[k4];
        float4 h1 = hrow[1024 + k4];
        #pragma unroll
        for (int j = 0; j < 12; j++) {
            int p = w * 12 + j;
            float4 wv = hw4[(size_t)p * 1024 + k4];
            acc0[j] += wv.x * h0.x + wv.y * h0.y + wv.z * h0.z + wv.w * h0.w;
            acc1[j] += wv.x * h1.x + wv.y * h1.y + wv.z * h1.z + wv.w * h1.w;
        }
    }

    int b0 = r0 >> 5, c0 = r0 & 31;
    int b1 = (r0 + 1) >> 5, c1 = (r0 + 1) & 31;
    float m0 = means[r0], s0 = stdev[r0];
    float m1 = means[r0 + 1], s1 = stdev[r0 + 1];
    #pragma unroll
    for (int j = 0; j < 12; j++) {
        float a0 = acc0[j], a1 = acc1[j];
        #pragma unroll
        for (int o = 1; o < 64; o <<= 1) {
            a0 += __shfl_xor(a0, o, 64);
            a1 += __shfl_xor(a1, o, 64);
        }
        if (l == 0) {
            int p = w * 12 + j;
            float hb = head_b[p];
            out[((size_t)b0 * PRED + p) * NVARS + c0] = (a0 + hb) * s0 + m0;
            out[((size_t)b1 * PRED + p) * NVARS + c1] = (a1 + hb) * s1 + m1;
        }
    }
}

// ---------------------------------------------------------------------------
extern "C" void kernel_launch(void* const* d_in, const int* in_sizes, int n_in,
                              void* d_out, int out_size, void* d_ws, size_t ws_size,
                              hipStream_t stream)
{
    const float* x_enc   = (const float*)d_in[0];
    const float* patch_w = (const float*)d_in[4];
    const float* norm_w  = (const float*)d_in[5];
    const float* in_w    = (const float*)d_in[6];
    const float* conv_w  = (const float*)d_in[7];
    const float* conv_b  = (const float*)d_in[8];
    const float* xp_w    = (const float*)d_in[9];
    const float* dt_w    = (const float*)d_in[10];
    const float* dt_b    = (const float*)d_in[11];
    const float* A_log   = (const float*)d_in[12];
    const float* D_skip  = (const float*)d_in[13];
    const float* out_w   = (const float*)d_in[14];
    const float* fnorm_w = (const float*)d_in[15];
    const float* head_w  = (const float*)d_in[16];
    const float* head_b  = (const float*)d_in[17];
    float* out = (float*)d_out;

    float* ws    = (float*)d_ws;
    float* means = ws;                    // 512
    float* stdv  = ws + 512;              // 512
    float* x     = ws + 1024;             // 16384*128
    float* h     = x  + (size_t)NTOK * DMODEL;
    float* xz    = h  + (size_t)NTOK * DMODEL;
    float* u     = xz + (size_t)NTOK * 2 * DIN;
    float* dtb   = u  + (size_t)NTOK * DIN;
    float* xdbl  = dtb + (size_t)NTOK * DIN;
    float* ybuf  = dtb;                   // alias: safe (chunk read-then-write)

    k_instnorm_patch<<<BATCH * NVARS, 256, 0, stream>>>(x_enc, patch_w, x, means, stdv);

    for (int layer = 0; layer < NLAYER; layer++) {
        const float* nw  = norm_w + layer * DMODEL;
        const float* iw  = in_w   + (size_t)layer * 2 * DIN * DMODEL;
        const float* cw  = conv_w + layer * DIN * DCONV;
        const float* cb  = conv_b + layer * DIN;
        const float* xw  = xp_w   + (size_t)layer * (DTRANK + 2 * DSTATE) * DIN;
        const float* dw  = dt_w   + layer * DIN * DTRANK;
        const float* db  = dt_b   + layer * DIN;
        const float* al  = A_log  + layer * DIN * DSTATE;
        const float* dp  = D_skip + layer * DIN;
        const float* ow  = out_w  + (size_t)layer * DMODEL * DIN;

        k_rmsnorm<<<NTOK / 4, 256, 0, stream>>>(x, nw, h);
        gemm_nt<false><<<dim3((2 * DIN) / 64, NTOK / 64), 256, 0, stream>>>(
            h, iw, xz, NTOK, 2 * DIN, DMODEL);
        k_conv<<<(NTOK * DIN) / 256, 256, 0, stream>>>(xz, cw, cb, u);
        gemm_nt<false><<<dim3(1, NTOK / 64), 256, 0, stream>>>(
            u, xw, xdbl, NTOK, DTRANK + 2 * DSTATE, DIN);
        k_dt<<<(NTOK * DIN) / 256, 256, 0, stream>>>(xdbl, dw, db, dtb);
        k_scan<<<BATCH * (DIN / 16), 256, 0, stream>>>(u, dtb, xdbl, xz, al, dp, ybuf);
        gemm_nt<true><<<dim3(DMODEL / 64, NTOK / 64), 256, 0, stream>>>(
            ybuf, ow, x, NTOK, DMODEL, DIN);
    }

    // final norm -> h, then fused head (gemm + bias + denorm + transpose)
    k_rmsnorm<<<NTOK / 4, 256, 0, stream>>>(x, fnorm_w, h);
    k_head<<<(BATCH * NVARS) / 2, 512, 0, stream>>>(h, head_w, head_b, means, stdv, out);
}

// Round 3
// 406.866 us; speedup vs baseline: 3.7825x; 2.2413x over previous
//
#include <hip/hip_runtime.h>
#include <hip/hip_bf16.h>
#include <math.h>

#define BATCH   16
#define SEQL    512
#define NVARS   32
#define PATCHL  16
#define LTOK    32
#define DMODEL  128
#define NLAYER  2
#define DIN     256
#define DSTATE  16
#define DTRANK  8
#define DCONV   4
#define PRED    96
#define TOK     1024
#define NTOK    (BATCH*TOK)   // 16384
#define EPSF    1e-5f
#define NCH     32            // time chunks
#define CHL     32            // TOK/NCH

// ---------------------------------------------------------------------------
// K1: per-(b,c) instance norm over time + patch embedding
// ---------------------------------------------------------------------------
__global__ __launch_bounds__(256) void k_instnorm_patch(
    const float* __restrict__ x_enc, const float* __restrict__ patch_w,
    float* __restrict__ x, float* __restrict__ means, float* __restrict__ stdev)
{
    int bc = blockIdx.x;
    int b = bc >> 5, c = bc & 31;
    __shared__ float xe[SEQL];
    __shared__ float pw[DMODEL * PATCHL];
    __shared__ float red[8];
    int tid = threadIdx.x;

    float v0 = x_enc[((size_t)b * SEQL + tid) * NVARS + c];
    float v1 = x_enc[((size_t)b * SEQL + tid + 256) * NVARS + c];
    for (int i = tid; i < DMODEL * PATCHL; i += 256) pw[i] = patch_w[i];

    float s = v0 + v1;
    for (int o = 1; o < 64; o <<= 1) s += __shfl_xor(s, o, 64);
    if ((tid & 63) == 0) red[tid >> 6] = s;
    __syncthreads();
    float mean = (red[0] + red[1] + red[2] + red[3]) * (1.f / 512.f);

    float d0 = v0 - mean, d1 = v1 - mean;
    float q = d0 * d0 + d1 * d1;
    for (int o = 1; o < 64; o <<= 1) q += __shfl_xor(q, o, 64);
    if ((tid & 63) == 0) red[4 + (tid >> 6)] = q;
    __syncthreads();
    float var = (red[4] + red[5] + red[6] + red[7]) * (1.f / 512.f);
    float sd = sqrtf(var + EPSF);
    float rsd = 1.f / sd;
    if (tid == 0) { means[bc] = mean; stdev[bc] = sd; }

    xe[tid] = d0 * rsd;
    xe[tid + 256] = d1 * rsd;
    __syncthreads();

    size_t base = ((size_t)b * TOK + (size_t)c * LTOK) * DMODEL;
    for (int o = tid; o < LTOK * DMODEL; o += 256) {
        int l = o >> 7, dm = o & 127;
        float acc = 0.f;
        #pragma unroll
        for (int p = 0; p < PATCHL; p++) acc += xe[l * PATCHL + p] * pw[dm * PATCHL + p];
        x[base + o] = acc;
    }
}

// ---------------------------------------------------------------------------
// K2: RMSNorm over last dim (128). One wave per token.
// ---------------------------------------------------------------------------
__global__ __launch_bounds__(256) void k_rmsnorm(
    const float* __restrict__ in, const float* __restrict__ w,
    float* __restrict__ out)
{
    int wave = threadIdx.x >> 6, lane = threadIdx.x & 63;
    int tok = blockIdx.x * 4 + wave;
    const float* r = in + (size_t)tok * DMODEL;
    float a = r[lane], bv = r[lane + 64];
    float q = a * a + bv * bv;
    for (int o = 1; o < 64; o <<= 1) q += __shfl_xor(q, o, 64);
    float rms = rsqrtf(q * (1.f / DMODEL) + EPSF);
    float* o_ = out + (size_t)tok * DMODEL;
    o_[lane]      = a  * rms * w[lane];
    o_[lane + 64] = bv * rms * w[lane + 64];
}

// ---------------------------------------------------------------------------
// K3: f32 GEMM  C[M,N] (+)= A[M,K](lda) @ W[N,K]^T (packed)
// 64x64 tile, BK=16, 256 threads, 4x4 micro-tile, float4 staging + frags.
// ---------------------------------------------------------------------------
template <bool ADD>
__global__ __launch_bounds__(256) void gemm_nt(
    const float* __restrict__ A, const float* __restrict__ W,
    float* __restrict__ C, int M, int N, int K, int lda)
{
    const int BM = 64, BN = 64, BK = 16;
    __shared__ float As[BK][BM + 4];
    __shared__ float Ws[BK][BN + 4];
    int bm = blockIdx.y * BM, bn = blockIdx.x * BN;
    int tid = threadIdx.x;
    int tx = tid & 15, ty = tid >> 4;
    float acc[4][4] = {};

    for (int k0 = 0; k0 < K; k0 += BK) {
        {   // stage A: 64 rows x 16 k, float4 per thread
            int m = tid >> 2, k = (tid & 3) * 4;
            float4 v = make_float4(0.f, 0.f, 0.f, 0.f);
            if (bm + m < M) v = *(const float4*)&A[(size_t)(bm + m) * lda + k0 + k];
            As[k][m] = v.x; As[k+1][m] = v.y; As[k+2][m] = v.z; As[k+3][m] = v.w;
        }
        {   // stage W
            int n = tid >> 2, k = (tid & 3) * 4;
            float4 v = make_float4(0.f, 0.f, 0.f, 0.f);
            if (bn + n < N) v = *(const float4*)&W[(size_t)(bn + n) * K + k0 + k];
            Ws[k][n] = v.x; Ws[k+1][n] = v.y; Ws[k+2][n] = v.z; Ws[k+3][n] = v.w;
        }
        __syncthreads();
        #pragma unroll
        for (int k = 0; k < BK; k++) {
            float4 a4 = *(const float4*)&As[k][ty * 4];
            float4 w4 = *(const float4*)&Ws[k][tx * 4];
            float a[4] = {a4.x, a4.y, a4.z, a4.w};
            float w[4] = {w4.x, w4.y, w4.z, w4.w};
            #pragma unroll
            for (int i = 0; i < 4; i++)
                #pragma unroll
                for (int j = 0; j < 4; j++) acc[i][j] += a[i] * w[j];
        }
        __syncthreads();
    }
    for (int i = 0; i < 4; i++) {
        int m = bm + ty * 4 + i;
        if (m >= M) continue;
        for (int j = 0; j < 4; j++) {
            int n = bn + tx * 4 + j;
            if (n >= N) continue;
            size_t idx = (size_t)m * N + n;
            if (ADD) C[idx] += acc[i][j]; else C[idx] = acc[i][j];
        }
    }
}

// ---------------------------------------------------------------------------
// K4: causal depthwise conv (k=4) + bias + SiLU
// ---------------------------------------------------------------------------
__global__ __launch_bounds__(256) void k_conv(
    const float* __restrict__ xz, const float* __restrict__ cw,
    const float* __restrict__ cb, float* __restrict__ u)
{
    int idx = blockIdx.x * 256 + threadIdx.x;
    int d = idx & 255;
    int t = (idx >> 8) & 1023;
    int b = idx >> 18;
    const float* col = xz + ((size_t)b * TOK) * 512 + d;
    float acc = cb[d];
    #pragma unroll
    for (int j = 0; j < DCONV; j++) {
        int tt = t - (DCONV - 1) + j;
        if (tt >= 0) acc += col[(size_t)tt * 512] * cw[d * DCONV + j];
    }
    u[idx] = acc / (1.f + __expf(-acc));
}

// ---------------------------------------------------------------------------
// Scan, chunked 3-phase. Thread owns one d, all 16 n-states in registers.
// dt = softplus(xdbl[:,0:8] @ dtw^T + b) computed inline.
// S1: per-chunk state with h0=0, plus sum(dt) (chunk decay = exp(A*sum_dt)).
// ---------------------------------------------------------------------------
__global__ __launch_bounds__(256) void k_scan1(
    const float* __restrict__ u, const float* __restrict__ xdbl,
    const float* __restrict__ dtw, const float* __restrict__ dtb_,
    const float* __restrict__ A_log,
    float* __restrict__ q, float* __restrict__ sdt_out)
{
    int blk = blockIdx.x;                 // b*NCH + ch
    int b = blk >> 5, ch = blk & (NCH - 1);
    int d = threadIdx.x;
    __shared__ float rows[CHL][40];
    const float* src = xdbl + ((size_t)b * TOK + ch * CHL) * 40;
    for (int i = d; i < CHL * 40; i += 256) rows[i / 40][i % 40] = src[i];

    float Av[16];
    #pragma unroll
    for (int n = 0; n < 16; n++) Av[n] = -__expf(A_log[d * 16 + n]);
    float w8[8];
    #pragma unroll
    for (int j = 0; j < 8; j++) w8[j] = dtw[d * 8 + j];
    float bias = dtb_[d];
    float h[16];
    #pragma unroll
    for (int n = 0; n < 16; n++) h[n] = 0.f;
    float sdt = 0.f;
    __syncthreads();

    for (int t = 0; t < CHL; t++) {
        size_t tok = (size_t)b * TOK + ch * CHL + t;
        float acc = bias;
        #pragma unroll
        for (int j = 0; j < 8; j++) acc += rows[t][j] * w8[j];
        float dtv = (acc > 20.f) ? acc : log1pf(__expf(acc));
        float uu = u[tok * 256 + d];
        sdt += dtv;
        float du = dtv * uu;
        #pragma unroll
        for (int n = 0; n < 16; n++)
            h[n] = __expf(dtv * Av[n]) * h[n] + du * rows[t][8 + n];
    }
    float* qp = q + ((size_t)blk * 256 + d) * 16;
    #pragma unroll
    for (int n = 0; n < 16; n += 4)
        *(float4*)(qp + n) = make_float4(h[n], h[n+1], h[n+2], h[n+3]);
    sdt_out[(size_t)blk * 256 + d] = sdt;
}

// S2: tiny cross-chunk scan; q is rewritten to hold h0 entering each chunk.
__global__ __launch_bounds__(256) void k_scan2(
    const float* __restrict__ A_log, const float* __restrict__ sdt_in,
    float* __restrict__ q)
{
    int idx = blockIdx.x * 256 + threadIdx.x;   // (b,d,n): 65536
    int n = idx & 15, d = (idx >> 4) & 255, b = idx >> 12;
    float Av = -__expf(A_log[d * 16 + n]);
    float h = 0.f;
    for (int ch = 0; ch < NCH; ch++) {
        size_t base = ((size_t)(b * NCH + ch) * 256 + d);
        float qv = q[base * 16 + n];
        float P = __expf(Av * sdt_in[base]);
        q[base * 16 + n] = h;
        h = P * h + qv;
    }
}

// S3: replay chunk with correct h0; y = (h·C + u*D)*silu(z).
// y overwrites xz low half (dead conv input); z read from high half.
__global__ __launch_bounds__(256) void k_scan3(
    const float* __restrict__ u, const float* __restrict__ xdbl,
    const float* __restrict__ dtw, const float* __restrict__ dtb_,
    const float* __restrict__ A_log, const float* __restrict__ Dp,
    const float* __restrict__ q, float* xz)
{
    int blk = blockIdx.x;
    int b = blk >> 5, ch = blk & (NCH - 1);
    int d = threadIdx.x;
    __shared__ float rows[CHL][40];
    const float* src = xdbl + ((size_t)b * TOK + ch * CHL) * 40;
    for (int i = d; i < CHL * 40; i += 256) rows[i / 40][i % 40] = src[i];

    float Av[16];
    #pragma unroll
    for (int n = 0; n < 16; n++) Av[n] = -__expf(A_log[d * 16 + n]);
    float w8[8];
    #pragma unroll
    for (int j = 0; j < 8; j++) w8[j] = dtw[d * 8 + j];
    float bias = dtb_[d];
    float Dv = Dp[d];
    float h[16];
    const float* qp = q + ((size_t)blk * 256 + d) * 16;
    #pragma unroll
    for (int n = 0; n < 16; n += 4) {
        float4 v = *(const float4*)(qp + n);
        h[n] = v.x; h[n+1] = v.y; h[n+2] = v.z; h[n+3] = v.w;
    }
    __syncthreads();

    for (int t = 0; t < CHL; t++) {
        size_t tok = (size_t)b * TOK + ch * CHL + t;
        float acc = bias;
        #pragma unroll
        for (int j = 0; j < 8; j++) acc += rows[t][j] * w8[j];
        float dtv = (acc > 20.f) ? acc : log1pf(__expf(acc));
        float uu = u[tok * 256 + d];
        float du = dtv * uu;
        float ya = 0.f;
        #pragma unroll
        for (int n = 0; n < 16; n++) {
            h[n] = __expf(dtv * Av[n]) * h[n] + du * rows[t][8 + n];
            ya += h[n] * rows[t][24 + n];
        }
        float zv = xz[tok * 512 + 256 + d];
        float sz = zv / (1.f + __expf(-zv));
        xz[tok * 512 + d] = (ya + uu * Dv) * sz;
    }
}

// ---------------------------------------------------------------------------
// K7: fused head (gemm + bias + denorm + transpose)
// ---------------------------------------------------------------------------
__global__ __launch_bounds__(512) void k_head(
    const float* __restrict__ hin, const float* __restrict__ head_w,
    const float* __restrict__ head_b,
    const float* __restrict__ means, const float* __restrict__ stdev,
    float* __restrict__ out)
{
    __shared__ float4 hrow[2 * 1024];
    int r0 = blockIdx.x * 2;
    int tid = threadIdx.x;
    const float4* src = (const float4*)(hin + (size_t)r0 * 4096);
    for (int i = tid; i < 2048; i += 512) hrow[i] = src[i];
    __syncthreads();

    int w = tid >> 6, l = tid & 63;
    float acc0[12], acc1[12];
    #pragma unroll
    for (int j = 0; j < 12; j++) { acc0[j] = 0.f; acc1[j] = 0.f; }

    const float4* hw4 = (const float4*)head_w;
    #pragma unroll 2
    for (int i = 0; i < 16; i++) {
        int k4 = l + 64 * i;
        float4 h0 = hrow[k4];
        float4 h1 = hrow[1024 + k4];
        #pragma unroll
        for (int j = 0; j < 12; j++) {
            int p = w * 12 + j;
            float4 wv = hw4[(size_t)p * 1024 + k4];
            acc0[j] += wv.x * h0.x + wv.y * h0.y + wv.z * h0.z + wv.w * h0.w;
            acc1[j] += wv.x * h1.x + wv.y * h1.y + wv.z * h1.z + wv.w * h1.w;
        }
    }

    int b0 = r0 >> 5, c0 = r0 & 31;
    int b1 = (r0 + 1) >> 5, c1 = (r0 + 1) & 31;
    float m0 = means[r0], s0 = stdev[r0];
    float m1 = means[r0 + 1], s1 = stdev[r0 + 1];
    #pragma unroll
    for (int j = 0; j < 12; j++) {
        float a0 = acc0[j], a1 = acc1[j];
        #pragma unroll
        for (int o = 1; o < 64; o <<= 1) {
            a0 += __shfl_xor(a0, o, 64);
            a1 += __shfl_xor(a1, o, 64);
        }
        if (l == 0) {
            int p = w * 12 + j;
            float hb = head_b[p];
            out[((size_t)b0 * PRED + p) * NVARS + c0] = (a0 + hb) * s0 + m0;
            out[((size_t)b1 * PRED + p) * NVARS + c1] = (a1 + hb) * s1 + m1;
        }
    }
}

// ---------------------------------------------------------------------------
extern "C" void kernel_launch(void* const* d_in, const int* in_sizes, int n_in,
                              void* d_out, int out_size, void* d_ws, size_t ws_size,
                              hipStream_t stream)
{
    const float* x_enc   = (const float*)d_in[0];
    const float* patch_w = (const float*)d_in[4];
    const float* norm_w  = (const float*)d_in[5];
    const float* in_w    = (const float*)d_in[6];
    const float* conv_w  = (const float*)d_in[7];
    const float* conv_b  = (const float*)d_in[8];
    const float* xp_w    = (const float*)d_in[9];
    const float* dt_w    = (const float*)d_in[10];
    const float* dt_b    = (const float*)d_in[11];
    const float* A_log   = (const float*)d_in[12];
    const float* D_skip  = (const float*)d_in[13];
    const float* out_w   = (const float*)d_in[14];
    const float* fnorm_w = (const float*)d_in[15];
    const float* head_w  = (const float*)d_in[16];
    const float* head_b  = (const float*)d_in[17];
    float* out = (float*)d_out;

    float* ws    = (float*)d_ws;
    float* means = ws;                          // 512
    float* stdv  = ws + 512;                    // 512
    float* x     = ws + 1024;                   // NTOK*128
    float* h     = x    + (size_t)NTOK * DMODEL;
    float* xz    = h    + (size_t)NTOK * DMODEL;      // NTOK*512 (y reuses low half)
    float* u     = xz   + (size_t)NTOK * 2 * DIN;     // NTOK*256
    float* xdbl  = u    + (size_t)NTOK * DIN;         // NTOK*40
    float* qbuf  = xdbl + (size_t)NTOK * 40;          // B*NCH*256*16
    float* sbuf  = qbuf + (size_t)BATCH * NCH * DIN * DSTATE; // B*NCH*256

    k_instnorm_patch<<<BATCH * NVARS, 256, 0, stream>>>(x_enc, patch_w, x, means, stdv);

    for (int layer = 0; layer < NLAYER; layer++) {
        const float* nw  = norm_w + layer * DMODEL;
        const float* iw  = in_w   + (size_t)layer * 2 * DIN * DMODEL;
        const float* cw  = conv_w + layer * DIN * DCONV;
        const float* cb  = conv_b + layer * DIN;
        const float* xw  = xp_w   + (size_t)layer * (DTRANK + 2 * DSTATE) * DIN;
        const float* dw  = dt_w   + layer * DIN * DTRANK;
        const float* db  = dt_b   + layer * DIN;
        const float* al  = A_log  + layer * DIN * DSTATE;
        const float* dp  = D_skip + layer * DIN;
        const float* ow  = out_w  + (size_t)layer * DMODEL * DIN;

        k_rmsnorm<<<NTOK / 4, 256, 0, stream>>>(x, nw, h);
        gemm_nt<false><<<dim3((2 * DIN) / 64, NTOK / 64), 256, 0, stream>>>(
            h, iw, xz, NTOK, 2 * DIN, DMODEL, DMODEL);
        k_conv<<<(NTOK * DIN) / 256, 256, 0, stream>>>(xz, cw, cb, u);
        gemm_nt<false><<<dim3(1, NTOK / 64), 256, 0, stream>>>(
            u, xw, xdbl, NTOK, DTRANK + 2 * DSTATE, DIN, DIN);
        k_scan1<<<BATCH * NCH, 256, 0, stream>>>(u, xdbl, dw, db, al, qbuf, sbuf);
        k_scan2<<<(BATCH * DIN * DSTATE) / 256, 256, 0, stream>>>(al, sbuf, qbuf);
        k_scan3<<<BATCH * NCH, 256, 0, stream>>>(u, xdbl, dw, db, al, dp, qbuf, xz);
        // x += y @ out_w^T   (y lives in xz low half, lda=512)
        gemm_nt<true><<<dim3(DMODEL / 64, NTOK / 64), 256, 0, stream>>>(
            xz, ow, x, NTOK, DMODEL, DIN, 2 * DIN);
    }

    k_rmsnorm<<<NTOK / 4, 256, 0, stream>>>(x, fnorm_w, h);
    k_head<<<(BATCH * NVARS) / 2, 512, 0, stream>>>(h, head_w, head_b, means, stdv, out);
}

// Round 4
// 325.938 us; speedup vs baseline: 4.7217x; 1.2483x over previous
//
#include <hip/hip_runtime.h>
#include <hip/hip_bf16.h>
#include <math.h>

#define BATCH   16
#define SEQL    512
#define NVARS   32
#define PATCHL  16
#define LTOK    32
#define DMODEL  128
#define NLAYER  2
#define DIN     256
#define DSTATE  16
#define DTRANK  8
#define DCONV   4
#define PRED    96
#define TOK     1024
#define NTOK    (BATCH*TOK)   // 16384
#define EPSF    1e-5f
#define NCH     64            // time chunks
#define CHL     16            // TOK/NCH

typedef __attribute__((ext_vector_type(8))) short bf16x8;
typedef __attribute__((ext_vector_type(4))) float f32x4;
typedef __hip_bfloat16 bf16;

// ---------------------------------------------------------------------------
// K0: cast all GEMM weights to bf16 (concatenated into wbf)
// ---------------------------------------------------------------------------
__global__ __launch_bounds__(256) void k_cast(
    const float* __restrict__ a, const float* __restrict__ b,
    const float* __restrict__ c, const float* __restrict__ d,
    int na, int nb, int nc, int nd, bf16* __restrict__ out)
{
    int i = blockIdx.x * 256 + threadIdx.x;
    int total = na + nb + nc + nd;
    if (i >= total) return;
    float v;
    if (i < na) v = a[i];
    else if (i < na + nb) v = b[i - na];
    else if (i < na + nb + nc) v = c[i - na - nb];
    else v = d[i - na - nb - nc];
    out[i] = __float2bfloat16(v);
}

// ---------------------------------------------------------------------------
// K1: per-(b,c) instance norm over time + patch embedding
// ---------------------------------------------------------------------------
__global__ __launch_bounds__(256) void k_instnorm_patch(
    const float* __restrict__ x_enc, const float* __restrict__ patch_w,
    float* __restrict__ x, float* __restrict__ means, float* __restrict__ stdev)
{
    int bc = blockIdx.x;
    int b = bc >> 5, c = bc & 31;
    __shared__ float xe[SEQL];
    __shared__ float pw[DMODEL * PATCHL];
    __shared__ float red[8];
    int tid = threadIdx.x;

    float v0 = x_enc[((size_t)b * SEQL + tid) * NVARS + c];
    float v1 = x_enc[((size_t)b * SEQL + tid + 256) * NVARS + c];
    for (int i = tid; i < DMODEL * PATCHL; i += 256) pw[i] = patch_w[i];

    float s = v0 + v1;
    for (int o = 1; o < 64; o <<= 1) s += __shfl_xor(s, o, 64);
    if ((tid & 63) == 0) red[tid >> 6] = s;
    __syncthreads();
    float mean = (red[0] + red[1] + red[2] + red[3]) * (1.f / 512.f);

    float d0 = v0 - mean, d1 = v1 - mean;
    float q = d0 * d0 + d1 * d1;
    for (int o = 1; o < 64; o <<= 1) q += __shfl_xor(q, o, 64);
    if ((tid & 63) == 0) red[4 + (tid >> 6)] = q;
    __syncthreads();
    float var = (red[4] + red[5] + red[6] + red[7]) * (1.f / 512.f);
    float sd = sqrtf(var + EPSF);
    float rsd = 1.f / sd;
    if (tid == 0) { means[bc] = mean; stdev[bc] = sd; }

    xe[tid] = d0 * rsd;
    xe[tid + 256] = d1 * rsd;
    __syncthreads();

    size_t base = ((size_t)b * TOK + (size_t)c * LTOK) * DMODEL;
    for (int o = tid; o < LTOK * DMODEL; o += 256) {
        int l = o >> 7, dm = o & 127;
        float acc = 0.f;
        #pragma unroll
        for (int p = 0; p < PATCHL; p++) acc += xe[l * PATCHL + p] * pw[dm * PATCHL + p];
        x[base + o] = acc;
    }
}

// ---------------------------------------------------------------------------
// K2: RMSNorm over last dim (128), bf16 output. One wave per token.
// ---------------------------------------------------------------------------
__global__ __launch_bounds__(256) void k_rmsnorm(
    const float* __restrict__ in, const float* __restrict__ w,
    bf16* __restrict__ out)
{
    int wave = threadIdx.x >> 6, lane = threadIdx.x & 63;
    int tok = blockIdx.x * 4 + wave;
    const float* r = in + (size_t)tok * DMODEL;
    float a = r[lane], bv = r[lane + 64];
    float q = a * a + bv * bv;
    for (int o = 1; o < 64; o <<= 1) q += __shfl_xor(q, o, 64);
    float rms = rsqrtf(q * (1.f / DMODEL) + EPSF);
    bf16* o_ = out + (size_t)tok * DMODEL;
    o_[lane]      = __float2bfloat16(a  * rms * w[lane]);
    o_[lane + 64] = __float2bfloat16(bv * rms * w[lane + 64]);
}

// ---------------------------------------------------------------------------
// K3: MFMA bf16 GEMM.  C[M,N] op= A[M,K](lda) @ W[N,K]^T  (f32 accum)
// 128x128 tile, BK=32, 4 waves (2x2), 16 MFMA(16x16x32)/wave/K-step.
// MODE: 0=store f32, 2=atomicAdd f32, 3=split (n<256 -> f32 C, else bf16 C2).
// gridDim.z = K-split; kper = K/gridDim.z (multiple of 32).
// Requires: M % 128 == 0, K % 32 == 0, lda % 8 == 0.
// ---------------------------------------------------------------------------
template <int MODE>
__global__ __launch_bounds__(256) void mfma_gemm(
    const bf16* __restrict__ A, const bf16* __restrict__ W,
    float* __restrict__ C, bf16* __restrict__ C2,
    int M, int N, int K, int lda, int kper)
{
    __shared__ ushort Asm[128][40];   // 80B row stride: frag reads 2-way only
    __shared__ ushort Wsm[128][40];
    int bm = blockIdx.y * 128, bn = blockIdx.x * 128;
    int tid = threadIdx.x;
    int w = tid >> 6, l = tid & 63;
    int wr = w >> 1, wc = w & 1;
    int kb = (l >> 4) * 8, lr = l & 15;

    f32x4 acc[4][4];
    #pragma unroll
    for (int i = 0; i < 4; i++)
        #pragma unroll
        for (int j = 0; j < 4; j++) acc[i][j] = (f32x4){0.f, 0.f, 0.f, 0.f};

    int kbeg = blockIdx.z * kper;
    for (int k0 = kbeg; k0 < kbeg + kper; k0 += 32) {
        #pragma unroll
        for (int i = 0; i < 2; i++) {
            int idx = tid + 256 * i;
            int row = idx >> 2, kq = (idx & 3) * 8;
            *(float4*)&Asm[row][kq] =
                *(const float4*)&A[(size_t)(bm + row) * lda + k0 + kq];
            float4 wv = make_float4(0.f, 0.f, 0.f, 0.f);
            if (bn + row < N)
                wv = *(const float4*)&W[(size_t)(bn + row) * K + k0 + kq];
            *(float4*)&Wsm[row][kq] = wv;
        }
        __syncthreads();
        bf16x8 af[4], bfr[4];
        #pragma unroll
        for (int f = 0; f < 4; f++) {
            af[f]  = *(const bf16x8*)&Asm[wr * 64 + f * 16 + lr][kb];
            bfr[f] = *(const bf16x8*)&Wsm[wc * 64 + f * 16 + lr][kb];
        }
        #pragma unroll
        for (int mf = 0; mf < 4; mf++)
            #pragma unroll
            for (int nf = 0; nf < 4; nf++)
                acc[mf][nf] = __builtin_amdgcn_mfma_f32_16x16x32_bf16(
                    af[mf], bfr[nf], acc[mf][nf], 0, 0, 0);
        __syncthreads();
    }

    // C/D layout: col = lane&15, row = (lane>>4)*4 + reg   [m89/m91 verified]
    int rbase = bm + wr * 64 + (l >> 4) * 4;
    int cbase = bn + wc * 64 + lr;
    #pragma unroll
    for (int mf = 0; mf < 4; mf++) {
        #pragma unroll
        for (int nf = 0; nf < 4; nf++) {
            int n = cbase + nf * 16;
            if (n >= N) continue;
            #pragma unroll
            for (int r = 0; r < 4; r++) {
                int m = rbase + mf * 16 + r;
                float v = acc[mf][nf][r];
                if (MODE == 0) C[(size_t)m * N + n] = v;
                else if (MODE == 2) atomicAdd(&C[(size_t)m * N + n], v);
                else {  // MODE 3: in_proj split store (N==512)
                    if (n < 256) C[(size_t)m * 256 + n] = v;
                    else C2[(size_t)m * 256 + (n - 256)] = __float2bfloat16(v);
                }
            }
        }
    }
}

// ---------------------------------------------------------------------------
// K4: causal depthwise conv (k=4) + bias + SiLU ; xs (f32, stride 256) -> u bf16
// ---------------------------------------------------------------------------
__global__ __launch_bounds__(256) void k_conv(
    const float* __restrict__ xs, const float* __restrict__ cw,
    const float* __restrict__ cb, bf16* __restrict__ ubf)
{
    int idx = blockIdx.x * 256 + threadIdx.x;
    int d = idx & 255;
    int t = (idx >> 8) & 1023;
    int b = idx >> 18;
    const float* col = xs + (size_t)b * TOK * 256 + d;
    float acc = cb[d];
    #pragma unroll
    for (int j = 0; j < DCONV; j++) {
        int tt = t - (DCONV - 1) + j;
        if (tt >= 0) acc += col[(size_t)tt * 256] * cw[d * DCONV + j];
    }
    float s = acc / (1.f + __expf(-acc));
    ubf[idx] = __float2bfloat16(s);
}

// ---------------------------------------------------------------------------
// Scan, chunked 3-phase (NCH=64, CHL=16). Thread owns one d, 16 n-states in reg.
// dt = softplus(xdbl[:,0:8] @ dtw^T + b) computed inline.
// ---------------------------------------------------------------------------
__global__ __launch_bounds__(256) void k_scan1(
    const bf16* __restrict__ ubf, const float* __restrict__ xdbl,
    const float* __restrict__ dtw, const float* __restrict__ dtb_,
    const float* __restrict__ A_log,
    float* __restrict__ q, float* __restrict__ sdt_out)
{
    int blk = blockIdx.x;                 // b*NCH + ch
    int b = blk >> 6, ch = blk & (NCH - 1);
    int d = threadIdx.x;
    __shared__ float rows[CHL][40];
    const float* src = xdbl + ((size_t)b * TOK + ch * CHL) * 40;
    for (int i = d; i < CHL * 40; i += 256) rows[i / 40][i % 40] = src[i];

    float Av[16];
    #pragma unroll
    for (int n = 0; n < 16; n++) Av[n] = -__expf(A_log[d * 16 + n]);
    float w8[8];
    #pragma unroll
    for (int j = 0; j < 8; j++) w8[j] = dtw[d * 8 + j];
    float bias = dtb_[d];
    float h[16];
    #pragma unroll
    for (int n = 0; n < 16; n++) h[n] = 0.f;
    float sdt = 0.f;
    __syncthreads();

    for (int t = 0; t < CHL; t++) {
        size_t tok = (size_t)b * TOK + ch * CHL + t;
        float acc = bias;
        #pragma unroll
        for (int j = 0; j < 8; j++) acc += rows[t][j] * w8[j];
        float dtv = (acc > 20.f) ? acc : log1pf(__expf(acc));
        float uu = __bfloat162float(ubf[tok * 256 + d]);
        sdt += dtv;
        float du = dtv * uu;
        #pragma unroll
        for (int n = 0; n < 16; n++)
            h[n] = __expf(dtv * Av[n]) * h[n] + du * rows[t][8 + n];
    }
    float* qp = q + ((size_t)blk * 256 + d) * 16;
    #pragma unroll
    for (int n = 0; n < 16; n += 4)
        *(float4*)(qp + n) = make_float4(h[n], h[n+1], h[n+2], h[n+3]);
    sdt_out[(size_t)blk * 256 + d] = sdt;
}

__global__ __launch_bounds__(256) void k_scan2(
    const float* __restrict__ A_log, const float* __restrict__ sdt_in,
    float* __restrict__ q)
{
    int idx = blockIdx.x * 256 + threadIdx.x;   // (b,d,n): 65536
    int n = idx & 15, d = (idx >> 4) & 255, b = idx >> 12;
    float Av = -__expf(A_log[d * 16 + n]);
    float h = 0.f;
    for (int ch = 0; ch < NCH; ch++) {
        size_t base = ((size_t)(b * NCH + ch) * 256 + d);
        float qv = q[base * 16 + n];
        float P = __expf(Av * sdt_in[base]);
        q[base * 16 + n] = h;
        h = P * h + qv;
    }
}

__global__ __launch_bounds__(256) void k_scan3(
    const bf16* __restrict__ ubf, const float* __restrict__ xdbl,
    const float* __restrict__ dtw, const float* __restrict__ dtb_,
    const float* __restrict__ A_log, const float* __restrict__ Dp,
    const float* __restrict__ q, const bf16* __restrict__ zbf,
    bf16* __restrict__ ybf)
{
    int blk = blockIdx.x;
    int b = blk >> 6, ch = blk & (NCH - 1);
    int d = threadIdx.x;
    __shared__ float rows[CHL][40];
    const float* src = xdbl + ((size_t)b * TOK + ch * CHL) * 40;
    for (int i = d; i < CHL * 40; i += 256) rows[i / 40][i % 40] = src[i];

    float Av[16];
    #pragma unroll
    for (int n = 0; n < 16; n++) Av[n] = -__expf(A_log[d * 16 + n]);
    float w8[8];
    #pragma unroll
    for (int j = 0; j < 8; j++) w8[j] = dtw[d * 8 + j];
    float bias = dtb_[d];
    float Dv = Dp[d];
    float h[16];
    const float* qp = q + ((size_t)blk * 256 + d) * 16;
    #pragma unroll
    for (int n = 0; n < 16; n += 4) {
        float4 v = *(const float4*)(qp + n);
        h[n] = v.x; h[n+1] = v.y; h[n+2] = v.z; h[n+3] = v.w;
    }
    __syncthreads();

    for (int t = 0; t < CHL; t++) {
        size_t tok = (size_t)b * TOK + ch * CHL + t;
        float acc = bias;
        #pragma unroll
        for (int j = 0; j < 8; j++) acc += rows[t][j] * w8[j];
        float dtv = (acc > 20.f) ? acc : log1pf(__expf(acc));
        float uu = __bfloat162float(ubf[tok * 256 + d]);
        float du = dtv * uu;
        float ya = 0.f;
        #pragma unroll
        for (int n = 0; n < 16; n++) {
            h[n] = __expf(dtv * Av[n]) * h[n] + du * rows[t][8 + n];
            ya += h[n] * rows[t][24 + n];
        }
        float zv = __bfloat162float(zbf[tok * 256 + d]);
        float sz = zv / (1.f + __expf(-zv));
        ybf[tok * 256 + d] = __float2bfloat16((ya + uu * Dv) * sz);
    }
}

// ---------------------------------------------------------------------------
// K7: head epilogue: out[b,p,c] = (hg[(b*32+c)*96+p] + hb[p]) * stdev + mean
// ---------------------------------------------------------------------------
__global__ __launch_bounds__(256) void k_head_ep(
    const float* __restrict__ hg, const float* __restrict__ hb,
    const float* __restrict__ means, const float* __restrict__ stdev,
    float* __restrict__ out)
{
    int i = blockIdx.x * 256 + threadIdx.x;
    if (i >= BATCH * PRED * NVARS) return;
    int c = i & 31;
    int p = (i >> 5) % PRED;
    int b = i / (PRED * NVARS);
    float v = hg[((size_t)b * NVARS + c) * PRED + p] + hb[p];
    out[i] = v * stdev[b * NVARS + c] + means[b * NVARS + c];
}

// ---------------------------------------------------------------------------
extern "C" void kernel_launch(void* const* d_in, const int* in_sizes, int n_in,
                              void* d_out, int out_size, void* d_ws, size_t ws_size,
                              hipStream_t stream)
{
    const float* x_enc   = (const float*)d_in[0];
    const float* patch_w = (const float*)d_in[4];
    const float* norm_w  = (const float*)d_in[5];
    const float* in_w    = (const float*)d_in[6];
    const float* conv_w  = (const float*)d_in[7];
    const float* conv_b  = (const float*)d_in[8];
    const float* xp_w    = (const float*)d_in[9];
    const float* dt_w    = (const float*)d_in[10];
    const float* dt_b    = (const float*)d_in[11];
    const float* A_log   = (const float*)d_in[12];
    const float* D_skip  = (const float*)d_in[13];
    const float* out_w   = (const float*)d_in[14];
    const float* fnorm_w = (const float*)d_in[15];
    const float* head_w  = (const float*)d_in[16];
    const float* head_b  = (const float*)d_in[17];
    float* out = (float*)d_out;

    // workspace carve (all f32-elem offsets; ~74 MB total)
    float* ws    = (float*)d_ws;
    float* means = ws;                          // 512
    float* stdv  = ws + 512;                    // 512
    float* x     = ws + 1024;                   // NTOK*128       8MB
    float* xs    = x    + (size_t)NTOK * 128;   // NTOK*256      16MB
    float* xdbl  = xs   + (size_t)NTOK * 256;   // NTOK*40      2.6MB
    float* qbuf  = xdbl + (size_t)NTOK * 40;    // 16*64*256*16  16.8MB
    float* sbuf  = qbuf + (size_t)BATCH * NCH * DIN * DSTATE;  // 1MB
    float* hg    = sbuf + (size_t)BATCH * NCH * DIN;           // 512*96
    bf16* hbf = (bf16*)(hg + 512 * PRED);       // NTOK*128   4MB
    bf16* zbf = hbf + (size_t)NTOK * 128;       // NTOK*256   8MB
    bf16* ubf = zbf + (size_t)NTOK * 256;       // NTOK*256   8MB
    bf16* ybf = ubf + (size_t)NTOK * 256;       // NTOK*256   8MB
    bf16* wbf = ybf + (size_t)NTOK * 256;       // 610304     1.2MB

    const int NIW = NLAYER * 2 * DIN * DMODEL;         // 131072
    const int NXW = NLAYER * (DTRANK + 2*DSTATE) * DIN;// 20480
    const int NOW = NLAYER * DMODEL * DIN;             // 65536
    const int NHW = PRED * LTOK * DMODEL;              // 393216
    bf16* iwbf = wbf;
    bf16* xwbf = iwbf + NIW;
    bf16* owbf = xwbf + NXW;
    bf16* hwbf = owbf + NOW;

    k_cast<<<(NIW + NXW + NOW + NHW + 255) / 256, 256, 0, stream>>>(
        in_w, xp_w, out_w, head_w, NIW, NXW, NOW, NHW, wbf);

    k_instnorm_patch<<<BATCH * NVARS, 256, 0, stream>>>(x_enc, patch_w, x, means, stdv);

    for (int layer = 0; layer < NLAYER; layer++) {
        const float* nw  = norm_w + layer * DMODEL;
        const float* cw  = conv_w + layer * DIN * DCONV;
        const float* cb  = conv_b + layer * DIN;
        const float* dw  = dt_w   + layer * DIN * DTRANK;
        const float* db  = dt_b   + layer * DIN;
        const float* al  = A_log  + layer * DIN * DSTATE;
        const float* dp  = D_skip + layer * DIN;
        const bf16* iw = iwbf + (size_t)layer * 2 * DIN * DMODEL;
        const bf16* xw = xwbf + (size_t)layer * (DTRANK + 2 * DSTATE) * DIN;
        const bf16* ow = owbf + (size_t)layer * DMODEL * DIN;

        k_rmsnorm<<<NTOK / 4, 256, 0, stream>>>(x, nw, hbf);
        // xz = h @ in_w^T, split-store: cols 0..255 -> xs (f32), 256..511 -> zbf (bf16)
        mfma_gemm<3><<<dim3(4, NTOK / 128, 1), 256, 0, stream>>>(
            hbf, iw, xs, zbf, NTOK, 512, DMODEL, DMODEL, DMODEL);
        k_conv<<<(NTOK * DIN) / 256, 256, 0, stream>>>(xs, cw, cb, ubf);
        // xdbl = u @ xp_w^T
        mfma_gemm<0><<<dim3(1, NTOK / 128, 1), 256, 0, stream>>>(
            ubf, xw, xdbl, nullptr, NTOK, DTRANK + 2 * DSTATE, DIN, DIN, DIN);
        k_scan1<<<BATCH * NCH, 256, 0, stream>>>(ubf, xdbl, dw, db, al, qbuf, sbuf);
        k_scan2<<<(BATCH * DIN * DSTATE) / 256, 256, 0, stream>>>(al, sbuf, qbuf);
        k_scan3<<<BATCH * NCH, 256, 0, stream>>>(ubf, xdbl, dw, db, al, dp, qbuf, zbf, ybf);
        // x += y @ out_w^T  (split-K=2, atomicAdd into residual)
        mfma_gemm<2><<<dim3(1, NTOK / 128, 2), 256, 0, stream>>>(
            ybf, ow, x, nullptr, NTOK, DMODEL, DIN, DIN, DIN / 2);
    }

    // final norm -> hbf; head = split-K MFMA into zeroed hg, then epilogue
    k_rmsnorm<<<NTOK / 4, 256, 0, stream>>>(x, fnorm_w, hbf);
    hipMemsetAsync(hg, 0, 512 * PRED * sizeof(float), stream);
    mfma_gemm<2><<<dim3(1, 4, 32), 256, 0, stream>>>(
        hbf, hwbf, hg, nullptr, 512, PRED, LTOK * DMODEL, LTOK * DMODEL, 128);
    k_head_ep<<<(BATCH * PRED * NVARS + 255) / 256, 256, 0, stream>>>(
        hg, head_b, means, stdv, out);
}

// Round 5
// 256.871 us; speedup vs baseline: 5.9912x; 1.2689x over previous
//
#include <hip/hip_runtime.h>
#include <hip/hip_bf16.h>
#include <math.h>

#define BATCH   16
#define SEQL    512
#define NVARS   32
#define PATCHL  16
#define LTOK    32
#define DMODEL  128
#define NLAYER  2
#define DIN     256
#define DSTATE  16
#define DTRANK  8
#define DCONV   4
#define PRED    96
#define TOK     1024
#define NTOK    (BATCH*TOK)   // 16384
#define EPSF    1e-5f
#define NCH     64            // time chunks
#define CHL     16            // TOK/NCH

typedef __attribute__((ext_vector_type(8))) short bf16x8;
typedef __attribute__((ext_vector_type(4))) float f32x4;
typedef __hip_bfloat16 bf16;

// ---------------------------------------------------------------------------
// K0: cast all GEMM weights to bf16 (concatenated into wbf)
// ---------------------------------------------------------------------------
__global__ __launch_bounds__(256) void k_cast(
    const float* __restrict__ a, const float* __restrict__ b,
    const float* __restrict__ c, const float* __restrict__ d,
    int na, int nb, int nc, int nd, bf16* __restrict__ out)
{
    int i = blockIdx.x * 256 + threadIdx.x;
    int total = na + nb + nc + nd;
    if (i >= total) return;
    float v;
    if (i < na) v = a[i];
    else if (i < na + nb) v = b[i - na];
    else if (i < na + nb + nc) v = c[i - na - nb];
    else v = d[i - na - nb - nc];
    out[i] = __float2bfloat16(v);
}

// ---------------------------------------------------------------------------
// K1: per-(b,c) instance norm over time + patch embedding
// ---------------------------------------------------------------------------
__global__ __launch_bounds__(256) void k_instnorm_patch(
    const float* __restrict__ x_enc, const float* __restrict__ patch_w,
    float* __restrict__ x, float* __restrict__ means, float* __restrict__ stdev)
{
    int bc = blockIdx.x;
    int b = bc >> 5, c = bc & 31;
    __shared__ float xe[SEQL];
    __shared__ float pw[DMODEL * PATCHL];
    __shared__ float red[8];
    int tid = threadIdx.x;

    float v0 = x_enc[((size_t)b * SEQL + tid) * NVARS + c];
    float v1 = x_enc[((size_t)b * SEQL + tid + 256) * NVARS + c];
    for (int i = tid; i < DMODEL * PATCHL; i += 256) pw[i] = patch_w[i];

    float s = v0 + v1;
    for (int o = 1; o < 64; o <<= 1) s += __shfl_xor(s, o, 64);
    if ((tid & 63) == 0) red[tid >> 6] = s;
    __syncthreads();
    float mean = (red[0] + red[1] + red[2] + red[3]) * (1.f / 512.f);

    float d0 = v0 - mean, d1 = v1 - mean;
    float q = d0 * d0 + d1 * d1;
    for (int o = 1; o < 64; o <<= 1) q += __shfl_xor(q, o, 64);
    if ((tid & 63) == 0) red[4 + (tid >> 6)] = q;
    __syncthreads();
    float var = (red[4] + red[5] + red[6] + red[7]) * (1.f / 512.f);
    float sd = sqrtf(var + EPSF);
    float rsd = 1.f / sd;
    if (tid == 0) { means[bc] = mean; stdev[bc] = sd; }

    xe[tid] = d0 * rsd;
    xe[tid + 256] = d1 * rsd;
    __syncthreads();

    size_t base = ((size_t)b * TOK + (size_t)c * LTOK) * DMODEL;
    for (int o = tid; o < LTOK * DMODEL; o += 256) {
        int l = o >> 7, dm = o & 127;
        float acc = 0.f;
        #pragma unroll
        for (int p = 0; p < PATCHL; p++) acc += xe[l * PATCHL + p] * pw[dm * PATCHL + p];
        x[base + o] = acc;
    }
}

// ---------------------------------------------------------------------------
// K2: RMSNorm over last dim (128), bf16 output. One wave per token.
// ---------------------------------------------------------------------------
__global__ __launch_bounds__(256) void k_rmsnorm(
    const float* __restrict__ in, const float* __restrict__ w,
    bf16* __restrict__ out)
{
    int wave = threadIdx.x >> 6, lane = threadIdx.x & 63;
    int tok = blockIdx.x * 4 + wave;
    const float* r = in + (size_t)tok * DMODEL;
    float a = r[lane], bv = r[lane + 64];
    float q = a * a + bv * bv;
    for (int o = 1; o < 64; o <<= 1) q += __shfl_xor(q, o, 64);
    float rms = rsqrtf(q * (1.f / DMODEL) + EPSF);
    bf16* o_ = out + (size_t)tok * DMODEL;
    o_[lane]      = __float2bfloat16(a  * rms * w[lane]);
    o_[lane + 64] = __float2bfloat16(bv * rms * w[lane + 64]);
}

// ---------------------------------------------------------------------------
// K3: MFMA bf16 GEMM.  C op= A[M,K](lda) @ W[N,K]^T  (f32 accum)
// 128x128 tile, BK=32, 4 waves (2x2), 16 MFMA(16x16x32)/wave/K-step.
// MODE: 0=store f32 C, 2=atomicAdd f32 C, 3=split bf16 (n<256 -> C3, else C2).
// ---------------------------------------------------------------------------
template <int MODE>
__global__ __launch_bounds__(256) void mfma_gemm(
    const bf16* __restrict__ A, const bf16* __restrict__ W,
    float* __restrict__ C, bf16* __restrict__ C2, bf16* __restrict__ C3,
    int M, int N, int K, int lda, int kper)
{
    __shared__ ushort Asm[128][40];   // 80B row stride: frag reads 2-way only
    __shared__ ushort Wsm[128][40];
    int bm = blockIdx.y * 128, bn = blockIdx.x * 128;
    int tid = threadIdx.x;
    int w = tid >> 6, l = tid & 63;
    int wr = w >> 1, wc = w & 1;
    int kb = (l >> 4) * 8, lr = l & 15;

    f32x4 acc[4][4];
    #pragma unroll
    for (int i = 0; i < 4; i++)
        #pragma unroll
        for (int j = 0; j < 4; j++) acc[i][j] = (f32x4){0.f, 0.f, 0.f, 0.f};

    int kbeg = blockIdx.z * kper;
    for (int k0 = kbeg; k0 < kbeg + kper; k0 += 32) {
        #pragma unroll
        for (int i = 0; i < 2; i++) {
            int idx = tid + 256 * i;
            int row = idx >> 2, kq = (idx & 3) * 8;
            *(float4*)&Asm[row][kq] =
                *(const float4*)&A[(size_t)(bm + row) * lda + k0 + kq];
            float4 wv = make_float4(0.f, 0.f, 0.f, 0.f);
            if (bn + row < N)
                wv = *(const float4*)&W[(size_t)(bn + row) * K + k0 + kq];
            *(float4*)&Wsm[row][kq] = wv;
        }
        __syncthreads();
        bf16x8 af[4], bfr[4];
        #pragma unroll
        for (int f = 0; f < 4; f++) {
            af[f]  = *(const bf16x8*)&Asm[wr * 64 + f * 16 + lr][kb];
            bfr[f] = *(const bf16x8*)&Wsm[wc * 64 + f * 16 + lr][kb];
        }
        #pragma unroll
        for (int mf = 0; mf < 4; mf++)
            #pragma unroll
            for (int nf = 0; nf < 4; nf++)
                acc[mf][nf] = __builtin_amdgcn_mfma_f32_16x16x32_bf16(
                    af[mf], bfr[nf], acc[mf][nf], 0, 0, 0);
        __syncthreads();
    }

    // C/D layout: col = lane&15, row = (lane>>4)*4 + reg
    int rbase = bm + wr * 64 + (l >> 4) * 4;
    int cbase = bn + wc * 64 + lr;
    #pragma unroll
    for (int mf = 0; mf < 4; mf++) {
        #pragma unroll
        for (int nf = 0; nf < 4; nf++) {
            int n = cbase + nf * 16;
            if (n >= N) continue;
            #pragma unroll
            for (int r = 0; r < 4; r++) {
                int m = rbase + mf * 16 + r;
                float v = acc[mf][nf][r];
                if (MODE == 0) C[(size_t)m * N + n] = v;
                else if (MODE == 2) atomicAdd(&C[(size_t)m * N + n], v);
                else {  // MODE 3: in_proj split store (N==512), both bf16
                    if (n < 256) C3[(size_t)m * 256 + n] = __float2bfloat16(v);
                    else C2[(size_t)m * 256 + (n - 256)] = __float2bfloat16(v);
                }
            }
        }
    }
}

// ---------------------------------------------------------------------------
// K4: causal depthwise conv (k=4) + bias + SiLU ; xs bf16 -> u bf16
// ---------------------------------------------------------------------------
__global__ __launch_bounds__(256) void k_conv(
    const bf16* __restrict__ xs, const float* __restrict__ cw,
    const float* __restrict__ cb, bf16* __restrict__ ubf)
{
    int idx = blockIdx.x * 256 + threadIdx.x;
    int d = idx & 255;
    int t = (idx >> 8) & 1023;
    int b = idx >> 18;
    const bf16* col = xs + (size_t)b * TOK * 256 + d;
    float acc = cb[d];
    #pragma unroll
    for (int j = 0; j < DCONV; j++) {
        int tt = t - (DCONV - 1) + j;
        if (tt >= 0) acc += __bfloat162float(col[(size_t)tt * 256]) * cw[d * DCONV + j];
    }
    float s = __fdividef(acc, 1.f + __expf(-acc));
    ubf[idx] = __float2bfloat16(s);
}

// ---------------------------------------------------------------------------
// Scan, chunked 3-phase (NCH=64, CHL=16). Thread owns one d, 16 n-states.
// xdbl rows read via block-uniform global loads (-> s_load, no LDS).
// dA_n computed as powers of e1=exp(dt*A0) when A has the (n+1)*A0 structure
// (runtime-verified per thread; exact-exp fallback otherwise).
// ---------------------------------------------------------------------------
__device__ __forceinline__ float softplus_f(float x) {
    return (x > 8.f) ? x : __logf(1.f + __expf(x));
}

__global__ __launch_bounds__(256) void k_scan1(
    const bf16* __restrict__ ubf, const float* __restrict__ xdbl,
    const float* __restrict__ dtw, const float* __restrict__ dtb_,
    const float* __restrict__ A_log,
    float* __restrict__ q, float* __restrict__ sdt_out)
{
    int blk = blockIdx.x;                 // b*NCH + ch
    int b = blk >> 6, ch = blk & (NCH - 1);
    int d = threadIdx.x;

    float a1 = -__expf(A_log[d * 16]);
    bool pw = true;
    #pragma unroll
    for (int n = 1; n < 16; n++) {
        float av = -__expf(A_log[d * 16 + n]);
        pw = pw && (fabsf(av - (n + 1) * a1) <= 1e-5f * fabsf((n + 1) * a1));
    }
    float w8[8];
    #pragma unroll
    for (int j = 0; j < 8; j++) w8[j] = dtw[d * 8 + j];
    float bias = dtb_[d];
    float h[16];
    #pragma unroll
    for (int n = 0; n < 16; n++) h[n] = 0.f;
    float sdt = 0.f;

    const float* row = xdbl + ((size_t)b * TOK + ch * CHL) * 40;
    const bf16* up = ubf + ((size_t)b * TOK + ch * CHL) * 256 + d;

    if (pw) {
        for (int t = 0; t < CHL; t++, row += 40, up += 256) {
            float acc = bias;
            #pragma unroll
            for (int j = 0; j < 8; j++) acc += row[j] * w8[j];
            float dtv = softplus_f(acc);
            float uu = __bfloat162float(*up);
            sdt += dtv;
            float du = dtv * uu;
            float dA[16];
            dA[0] = __expf(dtv * a1);
            #pragma unroll
            for (int n = 1; n < 16; n++) dA[n] = dA[(n - 1) >> 1] * dA[n >> 1];
            #pragma unroll
            for (int n = 0; n < 16; n++)
                h[n] = dA[n] * h[n] + du * row[8 + n];
        }
    } else {
        float Av[16];
        #pragma unroll
        for (int n = 0; n < 16; n++) Av[n] = -__expf(A_log[d * 16 + n]);
        for (int t = 0; t < CHL; t++, row += 40, up += 256) {
            float acc = bias;
            #pragma unroll
            for (int j = 0; j < 8; j++) acc += row[j] * w8[j];
            float dtv = softplus_f(acc);
            float uu = __bfloat162float(*up);
            sdt += dtv;
            float du = dtv * uu;
            #pragma unroll
            for (int n = 0; n < 16; n++)
                h[n] = __expf(dtv * Av[n]) * h[n] + du * row[8 + n];
        }
    }
    float* qp = q + ((size_t)blk * 256 + d) * 16;
    #pragma unroll
    for (int n = 0; n < 16; n += 4)
        *(float4*)(qp + n) = make_float4(h[n], h[n+1], h[n+2], h[n+3]);
    sdt_out[(size_t)blk * 256 + d] = sdt;
}

__global__ __launch_bounds__(256) void k_scan2(
    const float* __restrict__ A_log, const float* __restrict__ sdt_in,
    float* __restrict__ q)
{
    int idx = blockIdx.x * 256 + threadIdx.x;   // (b,d,n): 65536
    int n = idx & 15, d = (idx >> 4) & 255, b = idx >> 12;
    float Av = -__expf(A_log[d * 16 + n]);
    float h = 0.f;
    for (int ch = 0; ch < NCH; ch++) {
        size_t base = ((size_t)(b * NCH + ch) * 256 + d);
        float qv = q[base * 16 + n];
        float P = __expf(Av * sdt_in[base]);
        q[base * 16 + n] = h;
        h = P * h + qv;
    }
}

__global__ __launch_bounds__(256) void k_scan3(
    const bf16* __restrict__ ubf, const float* __restrict__ xdbl,
    const float* __restrict__ dtw, const float* __restrict__ dtb_,
    const float* __restrict__ A_log, const float* __restrict__ Dp,
    const float* __restrict__ q, const bf16* __restrict__ zbf,
    bf16* __restrict__ ybf)
{
    int blk = blockIdx.x;
    int b = blk >> 6, ch = blk & (NCH - 1);
    int d = threadIdx.x;

    float a1 = -__expf(A_log[d * 16]);
    bool pw = true;
    #pragma unroll
    for (int n = 1; n < 16; n++) {
        float av = -__expf(A_log[d * 16 + n]);
        pw = pw && (fabsf(av - (n + 1) * a1) <= 1e-5f * fabsf((n + 1) * a1));
    }
    float w8[8];
    #pragma unroll
    for (int j = 0; j < 8; j++) w8[j] = dtw[d * 8 + j];
    float bias = dtb_[d];
    float Dv = Dp[d];
    float h[16];
    const float* qp = q + ((size_t)blk * 256 + d) * 16;
    #pragma unroll
    for (int n = 0; n < 16; n += 4) {
        float4 v = *(const float4*)(qp + n);
        h[n] = v.x; h[n+1] = v.y; h[n+2] = v.z; h[n+3] = v.w;
    }

    const float* row = xdbl + ((size_t)b * TOK + ch * CHL) * 40;
    size_t tok0 = (size_t)b * TOK + ch * CHL;
    const bf16* up = ubf + tok0 * 256 + d;
    const bf16* zp = zbf + tok0 * 256 + d;
    bf16* yp = ybf + tok0 * 256 + d;

    if (pw) {
        for (int t = 0; t < CHL; t++, row += 40, up += 256, zp += 256, yp += 256) {
            float acc = bias;
            #pragma unroll
            for (int j = 0; j < 8; j++) acc += row[j] * w8[j];
            float dtv = softplus_f(acc);
            float uu = __bfloat162float(*up);
            float du = dtv * uu;
            float dA[16];
            dA[0] = __expf(dtv * a1);
            #pragma unroll
            for (int n = 1; n < 16; n++) dA[n] = dA[(n - 1) >> 1] * dA[n >> 1];
            float ya = 0.f;
            #pragma unroll
            for (int n = 0; n < 16; n++) {
                h[n] = dA[n] * h[n] + du * row[8 + n];
                ya += h[n] * row[24 + n];
            }
            float zv = __bfloat162float(*zp);
            float sz = __fdividef(zv, 1.f + __expf(-zv));
            *yp = __float2bfloat16((ya + uu * Dv) * sz);
        }
    } else {
        float Av[16];
        #pragma unroll
        for (int n = 0; n < 16; n++) Av[n] = -__expf(A_log[d * 16 + n]);
        for (int t = 0; t < CHL; t++, row += 40, up += 256, zp += 256, yp += 256) {
            float acc = bias;
            #pragma unroll
            for (int j = 0; j < 8; j++) acc += row[j] * w8[j];
            float dtv = softplus_f(acc);
            float uu = __bfloat162float(*up);
            float du = dtv * uu;
            float ya = 0.f;
            #pragma unroll
            for (int n = 0; n < 16; n++) {
                h[n] = __expf(dtv * Av[n]) * h[n] + du * row[8 + n];
                ya += h[n] * row[24 + n];
            }
            float zv = __bfloat162float(*zp);
            float sz = __fdividef(zv, 1.f + __expf(-zv));
            *yp = __float2bfloat16((ya + uu * Dv) * sz);
        }
    }
}

// ---------------------------------------------------------------------------
// K7: head epilogue: out[b,p,c] = (hg[(b*32+c)*96+p] + hb[p]) * stdev + mean
// ---------------------------------------------------------------------------
__global__ __launch_bounds__(256) void k_head_ep(
    const float* __restrict__ hg, const float* __restrict__ hb,
    const float* __restrict__ means, const float* __restrict__ stdev,
    float* __restrict__ out)
{
    int i = blockIdx.x * 256 + threadIdx.x;
    if (i >= BATCH * PRED * NVARS) return;
    int c = i & 31;
    int p = (i >> 5) % PRED;
    int b = i / (PRED * NVARS);
    float v = hg[((size_t)b * NVARS + c) * PRED + p] + hb[p];
    out[i] = v * stdev[b * NVARS + c] + means[b * NVARS + c];
}

// ---------------------------------------------------------------------------
extern "C" void kernel_launch(void* const* d_in, const int* in_sizes, int n_in,
                              void* d_out, int out_size, void* d_ws, size_t ws_size,
                              hipStream_t stream)
{
    const float* x_enc   = (const float*)d_in[0];
    const float* patch_w = (const float*)d_in[4];
    const float* norm_w  = (const float*)d_in[5];
    const float* in_w    = (const float*)d_in[6];
    const float* conv_w  = (const float*)d_in[7];
    const float* conv_b  = (const float*)d_in[8];
    const float* xp_w    = (const float*)d_in[9];
    const float* dt_w    = (const float*)d_in[10];
    const float* dt_b    = (const float*)d_in[11];
    const float* A_log   = (const float*)d_in[12];
    const float* D_skip  = (const float*)d_in[13];
    const float* out_w   = (const float*)d_in[14];
    const float* fnorm_w = (const float*)d_in[15];
    const float* head_w  = (const float*)d_in[16];
    const float* head_b  = (const float*)d_in[17];
    float* out = (float*)d_out;

    float* ws    = (float*)d_ws;
    float* means = ws;                          // 512
    float* stdv  = ws + 512;                    // 512
    float* x     = ws + 1024;                   // NTOK*128 f32   8MB
    float* xdbl  = x    + (size_t)NTOK * 128;   // NTOK*40      2.6MB
    float* qbuf  = xdbl + (size_t)NTOK * 40;    // 16*64*256*16  16.8MB
    float* sbuf  = qbuf + (size_t)BATCH * NCH * DIN * DSTATE;  // 1MB
    float* hg    = sbuf + (size_t)BATCH * NCH * DIN;           // 512*96
    bf16* hbf  = (bf16*)(hg + 512 * PRED);      // NTOK*128   4MB
    bf16* xsbf = hbf + (size_t)NTOK * 128;      // NTOK*256   8MB
    bf16* zbf  = xsbf + (size_t)NTOK * 256;     // NTOK*256   8MB
    bf16* ubf  = zbf + (size_t)NTOK * 256;      // NTOK*256   8MB
    bf16* ybf  = ubf + (size_t)NTOK * 256;      // NTOK*256   8MB
    bf16* wbf  = ybf + (size_t)NTOK * 256;      // 610304     1.2MB

    const int NIW = NLAYER * 2 * DIN * DMODEL;         // 131072
    const int NXW = NLAYER * (DTRANK + 2*DSTATE) * DIN;// 20480
    const int NOW = NLAYER * DMODEL * DIN;             // 65536
    const int NHW = PRED * LTOK * DMODEL;              // 393216
    bf16* iwbf = wbf;
    bf16* xwbf = iwbf + NIW;
    bf16* owbf = xwbf + NXW;
    bf16* hwbf = owbf + NOW;

    k_cast<<<(NIW + NXW + NOW + NHW + 255) / 256, 256, 0, stream>>>(
        in_w, xp_w, out_w, head_w, NIW, NXW, NOW, NHW, wbf);

    k_instnorm_patch<<<BATCH * NVARS, 256, 0, stream>>>(x_enc, patch_w, x, means, stdv);

    for (int layer = 0; layer < NLAYER; layer++) {
        const float* nw  = norm_w + layer * DMODEL;
        const float* cw  = conv_w + layer * DIN * DCONV;
        const float* cb  = conv_b + layer * DIN;
        const float* dw  = dt_w   + layer * DIN * DTRANK;
        const float* db  = dt_b   + layer * DIN;
        const float* al  = A_log  + layer * DIN * DSTATE;
        const float* dp  = D_skip + layer * DIN;
        const bf16* iw = iwbf + (size_t)layer * 2 * DIN * DMODEL;
        const bf16* xw = xwbf + (size_t)layer * (DTRANK + 2 * DSTATE) * DIN;
        const bf16* ow = owbf + (size_t)layer * DMODEL * DIN;

        k_rmsnorm<<<NTOK / 4, 256, 0, stream>>>(x, nw, hbf);
        // xz = h @ in_w^T, split: cols 0..255 -> xsbf, 256..511 -> zbf (bf16)
        mfma_gemm<3><<<dim3(4, NTOK / 128, 1), 256, 0, stream>>>(
            hbf, iw, nullptr, zbf, xsbf, NTOK, 512, DMODEL, DMODEL, DMODEL);
        k_conv<<<(NTOK * DIN) / 256, 256, 0, stream>>>(xsbf, cw, cb, ubf);
        // xdbl = u @ xp_w^T
        mfma_gemm<0><<<dim3(1, NTOK / 128, 1), 256, 0, stream>>>(
            ubf, xw, xdbl, nullptr, nullptr, NTOK, DTRANK + 2 * DSTATE, DIN, DIN, DIN);
        k_scan1<<<BATCH * NCH, 256, 0, stream>>>(ubf, xdbl, dw, db, al, qbuf, sbuf);
        k_scan2<<<(BATCH * DIN * DSTATE) / 256, 256, 0, stream>>>(al, sbuf, qbuf);
        k_scan3<<<BATCH * NCH, 256, 0, stream>>>(ubf, xdbl, dw, db, al, dp, qbuf, zbf, ybf);
        // x += y @ out_w^T  (split-K=2, atomicAdd into residual)
        mfma_gemm<2><<<dim3(1, NTOK / 128, 2), 256, 0, stream>>>(
            ybf, ow, x, nullptr, nullptr, NTOK, DMODEL, DIN, DIN, DIN / 2);
    }

    // final norm -> hbf; head = split-K MFMA into zeroed hg, then epilogue
    k_rmsnorm<<<NTOK / 4, 256, 0, stream>>>(x, fnorm_w, hbf);
    hipMemsetAsync(hg, 0, 512 * PRED * sizeof(float), stream);
    mfma_gemm<2><<<dim3(1, 4, 32), 256, 0, stream>>>(
        hbf, hwbf, hg, nullptr, nullptr, 512, PRED, LTOK * DMODEL, LTOK * DMODEL, 128);
    k_head_ep<<<(BATCH * PRED * NVARS + 255) / 256, 256, 0, stream>>>(
        hg, head_b, means, stdv, out);
}